// Round 5
// baseline (190.804 us; speedup 1.0000x reference)
//
#include <hip/hip_runtime.h>

#define N_IN   256
#define NCEN   2048
#define NOUT   128
#define BR     64
#define XP     264          // prologue-only padded X stride (shorts)
#define LOG2E  1.4426950408889634f

typedef __bf16 bf16x8 __attribute__((ext_vector_type(8)));
typedef float  f32x4  __attribute__((ext_vector_type(4)));

__device__ __forceinline__ unsigned short f2bf(float f) {
  unsigned int u = __builtin_bit_cast(unsigned int, f);
  u += 0x7FFFu + ((u >> 16) & 1u);            // round-to-nearest-even
  return (unsigned short)(u >> 16);
}

__device__ __forceinline__ bf16x8 ldfrag(const unsigned short* p) {
  return __builtin_bit_cast(bf16x8, *reinterpret_cast<const uint4*>(p));
}

// ---------------- prep: fp32 -> bf16 for centers & W, plus |c|^2 ----------------
__global__ __launch_bounds__(256) void rbfn_prep(
    const float* __restrict__ centers, const float* __restrict__ W,
    unsigned short* __restrict__ cbw, unsigned short* __restrict__ wbw,
    float* __restrict__ csq)
{
  const int b = blockIdx.x;
  const int tid = threadIdx.x;
  if (b < 512) {                      // centers: 4 rows per block, 1 wave per row
    const int wave = tid >> 6, lane = tid & 63;
    const int row = b * 4 + wave;
    float4 v = reinterpret_cast<const float4*>(centers + row * N_IN)[lane];
    float ss = v.x * v.x + v.y * v.y + v.z * v.z + v.w * v.w;
    ushort4 pk = { f2bf(v.x), f2bf(v.y), f2bf(v.z), f2bf(v.w) };
    reinterpret_cast<ushort4*>(cbw + row * N_IN)[lane] = pk;
    for (int off = 32; off > 0; off >>= 1) ss += __shfl_down(ss, off, 64);
    if (lane == 0) csq[row] = ss;
  } else {                            // W: flat float4 -> bf16x4
    const int f = (b - 512) * 256 + tid;   // 73728 float4 total, exact
    float4 v = reinterpret_cast<const float4*>(W)[f];
    ushort4 pk = { f2bf(v.x), f2bf(v.y), f2bf(v.z), f2bf(v.w) };
    reinterpret_cast<ushort4*>(wbw)[f] = pk;
  }
}

// ---------------- fused main kernel ----------------
// 256 WGs x 512 thr (8 waves), 64 rows/WG. Unified 36-iter loop:
//   it 0..3  : X-part of feats@W^T (A = register-resident X, B = W cols it*64)
//   it 4..35 : radial blocks rb=it-4 (cross GEMM -> exp2 -> feats GEMM)
// W columns are consumed exactly in order: WL colbase = it*64.
// Staging: global->VGPR prefetch at iter top, ds_write into ALT buffer at iter
// end -> all barriers are lgkm-only (no vmcnt(0) drain at any barrier).
// Wave tile: mw=wave&1 row-half (32 rows, A+C in regs), nw=wave>>1:
//   cross 16-center slice / feats 32-out slice. Each B-frag feeds 2 MFMAs (mt).
// LDS chunk-major (chunk=16B): CB chunk=(k>>3)*64+c; WL chunk=(k>>3)*128+o;
// R chunk=(c>>3)*64+row  -> all b128 reads/writes are 2-way-or-free on banks.
__global__ __launch_bounds__(512, 1) void rbfn_main(
    const float* __restrict__ X, const float* __restrict__ beta,
    const float* __restrict__ bias,
    const unsigned short* __restrict__ cbw,   // [2048][256] bf16
    const unsigned short* __restrict__ wbw,   // [128][2304] bf16
    const float* __restrict__ csq,            // [2048]
    float* __restrict__ out)                  // [16384][128] fp32
{
  __shared__ __align__(16) unsigned char pool[108800];
  unsigned short* const CB0 = (unsigned short*)(pool);            // 32 KB
  unsigned short* const CB1 = (unsigned short*)(pool + 32768);    // 32 KB
  unsigned short* const WL0 = (unsigned short*)(pool + 65536);    // 16 KB
  unsigned short* const WL1 = (unsigned short*)(pool + 81920);    // 16 KB
  unsigned short* const Rm  = (unsigned short*)(pool + 98304);    //  8 KB
  float* const xsq  = (float*)(pool + 106496);                    // 64 f
  float* const pred = (float*)(pool + 106752);                    // 512 f
  unsigned short* const Xb = (unsigned short*)pool;               // prologue alias (33.8 KB < 64 KB)

  const int tid  = threadIdx.x;
  const int wave = tid >> 6;
  const int lane = tid & 63;
  const int l16  = lane & 15;
  const int quad = lane >> 4;
  const int mw   = wave & 1;          // 32-row half
  const int nw   = wave >> 1;         // 0..3: cross 16c slice / feats 32o slice
  const int r0   = blockIdx.x * BR;

  // --- prologue: stage X tile fp32->bf16 into Xb, |x|^2 partials ---
  {
    const int row = tid >> 3;          // 0..63
    const int q   = tid & 7;
    const float4* gx = reinterpret_cast<const float4*>(X + (r0 + row) * N_IN) + q * 8;
    float ss = 0.f;
#pragma unroll
    for (int j = 0; j < 8; ++j) {
      float4 v = gx[j];
      ss += v.x * v.x + v.y * v.y + v.z * v.z + v.w * v.w;
      ushort4 pk = { f2bf(v.x), f2bf(v.y), f2bf(v.z), f2bf(v.w) };
      *reinterpret_cast<ushort4*>(&Xb[row * XP + q * 32 + j * 4]) = pk;
    }
    pred[tid] = ss;
  }
  __syncthreads();
  if (tid < 64) {
    float s = 0.f;
#pragma unroll
    for (int k = 0; k < 8; ++k) s += pred[tid * 8 + k];
    xsq[tid] = s;
  }

  // persistent A fragments: wave's 32 rows x 256 k (64 VGPR)
  bf16x8 areg[2][8];
#pragma unroll
  for (int mt = 0; mt < 2; ++mt)
#pragma unroll
    for (int kb = 0; kb < 8; ++kb)
      areg[mt][kb] = ldfrag(&Xb[(mw * 32 + mt * 16 + l16) * XP + kb * 32 + quad * 8]);

  // pre-stage WL for iter 0 (W cols 0..63): load to regs now, write after barrier
  uint4 wl0r[2];
#pragma unroll
  for (int j = 0; j < 2; ++j) {
    const int idx = j * 512 + tid;
    wl0r[j] = *reinterpret_cast<const uint4*>(wbw + (idx & 127) * 2304 + (idx >> 7) * 8);
  }
  __syncthreads();                     // xsq visible; Xb reads complete

  float xsqr[8];                       // this lane's 8 row |x|^2 values
#pragma unroll
  for (int mt = 0; mt < 2; ++mt)
#pragma unroll
    for (int r = 0; r < 4; ++r)
      xsqr[mt * 4 + r] = xsq[mw * 32 + mt * 16 + quad * 4 + r];

#pragma unroll
  for (int j = 0; j < 2; ++j)
    *reinterpret_cast<uint4*>(WL0 + (j * 512 + tid) * 8) = wl0r[j];

  f32x4 oacc[2][2] = {};               // 32 rows x 32 outs per wave

  for (int it = 0; it < 36; ++it) {
    __syncthreads();                   // lgkm-only: buffer(it) + R(it-1) ordering
    const int par = it & 1;
    const unsigned short* const CBb = par ? CB1 : CB0;
    const unsigned short* const WLb = par ? WL1 : WL0;

    // --- issue prefetch for it+1 into registers (consumed at iter end) ---
    uint4 wlr[2], cbr[4];
    const bool do_wl = (it < 35);
    const bool do_cb = (it >= 3 && it < 35);
    if (do_wl) {
#pragma unroll
      for (int j = 0; j < 2; ++j) {
        const int idx = j * 512 + tid;
        wlr[j] = *reinterpret_cast<const uint4*>(
            wbw + (idx & 127) * 2304 + (it + 1) * 64 + (idx >> 7) * 8);
      }
    }
    if (do_cb) {
#pragma unroll
      for (int j = 0; j < 4; ++j) {
        const int idx = j * 512 + tid;
        cbr[j] = *reinterpret_cast<const uint4*>(
            cbw + ((it - 3) * 64 + (idx & 63)) * 256 + (idx >> 6) * 8);
      }
    }

    if (it < 4) {
      // === X-part: oacc += X[:, it*64..] @ W[:, it*64..]^T, A from regs ===
#pragma unroll
      for (int ks = 0; ks < 2; ++ks)
#pragma unroll
        for (int ot = 0; ot < 2; ++ot) {
          bf16x8 bfr = ldfrag(&WLb[((ks * 4 + quad) * 128 + nw * 32 + ot * 16 + l16) * 8]);
#pragma unroll
          for (int mt = 0; mt < 2; ++mt)
            oacc[mt][ot] = __builtin_amdgcn_mfma_f32_16x16x32_bf16(
                areg[mt][it * 2 + ks], bfr, oacc[mt][ot], 0, 0, 0);
        }
    } else {
      const int rb   = it - 4;
      const int c_lo = nw * 16 + l16;
      const int cg   = rb * 64 + c_lo;
      const float my_cs  = csq[cg];
      const float my_nb2 = -LOG2E * beta[cg];

      // cross GEMM: 32r x 16c, K=256; each B-frag feeds 2 MFMAs
      f32x4 cacc[2] = {};
#pragma unroll
      for (int kb = 0; kb < 8; ++kb) {
        bf16x8 bfr = ldfrag(&CBb[((kb * 4 + quad) * 64 + c_lo) * 8]);
#pragma unroll
        for (int mt = 0; mt < 2; ++mt)
          cacc[mt] = __builtin_amdgcn_mfma_f32_16x16x32_bf16(
              areg[mt][kb], bfr, cacc[mt], 0, 0, 0);
      }

      // epilogue -> Rm (chunk-major bf16)
#pragma unroll
      for (int mt = 0; mt < 2; ++mt)
#pragma unroll
        for (int r = 0; r < 4; ++r) {
          const int row = mw * 32 + mt * 16 + quad * 4 + r;  // D: row=quad*4+reg
          float sd = xsqr[mt * 4 + r] + my_cs - 2.f * cacc[mt][r];
          Rm[((c_lo >> 3) * 64 + row) * 8 + (c_lo & 7)] = f2bf(exp2f(my_nb2 * sd));
        }
      asm volatile("s_waitcnt lgkmcnt(0)\n\ts_barrier" ::: "memory");  // R visible

      // feats GEMM: oacc += R[32r x 64c] @ W[:,cols]^T
#pragma unroll
      for (int ks = 0; ks < 2; ++ks) {
        bf16x8 afr[2], bfr[2];
#pragma unroll
        for (int mt = 0; mt < 2; ++mt)
          afr[mt] = ldfrag(&Rm[((ks * 4 + quad) * 64 + mw * 32 + mt * 16 + l16) * 8]);
#pragma unroll
        for (int ot = 0; ot < 2; ++ot)
          bfr[ot] = ldfrag(&WLb[((ks * 4 + quad) * 128 + nw * 32 + ot * 16 + l16) * 8]);
#pragma unroll
        for (int mt = 0; mt < 2; ++mt)
#pragma unroll
          for (int ot = 0; ot < 2; ++ot)
            oacc[mt][ot] = __builtin_amdgcn_mfma_f32_16x16x32_bf16(
                afr[mt], bfr[ot], oacc[mt][ot], 0, 0, 0);
      }
    }

    // --- write prefetched tiles into ALT buffers (vmcnt waits here, per-wave) ---
    if (do_wl) {
      unsigned short* const WLn = par ? WL0 : WL1;
#pragma unroll
      for (int j = 0; j < 2; ++j)
        *reinterpret_cast<uint4*>(WLn + (j * 512 + tid) * 8) = wlr[j];
    }
    if (do_cb) {
      unsigned short* const CBn = par ? CB0 : CB1;
#pragma unroll
      for (int j = 0; j < 4; ++j)
        *reinterpret_cast<uint4*>(CBn + (j * 512 + tid) * 8) = cbr[j];
    }
  }

  // --- final: add bias, store fp32 ---
#pragma unroll
  for (int ot = 0; ot < 2; ++ot) {
    const int o  = nw * 32 + ot * 16 + l16;
    const float bv = bias[o];
#pragma unroll
    for (int mt = 0; mt < 2; ++mt)
#pragma unroll
      for (int r = 0; r < 4; ++r) {
        const int row = r0 + mw * 32 + mt * 16 + quad * 4 + r;
        out[row * NOUT + o] = oacc[mt][ot][r] + bv;
      }
  }
}

extern "C" void kernel_launch(void* const* d_in, const int* in_sizes, int n_in,
                              void* d_out, int out_size, void* d_ws, size_t ws_size,
                              hipStream_t stream) {
  const float* X       = (const float*)d_in[0];   // [16384,256]
  const float* centers = (const float*)d_in[1];   // [2048,256]
  const float* beta    = (const float*)d_in[2];   // [1,2048]
  const float* W       = (const float*)d_in[3];   // [128,2304]
  const float* bias    = (const float*)d_in[4];   // [128]
  float* out = (float*)d_out;

  char* ws = (char*)d_ws;
  unsigned short* cbw = (unsigned short*)ws;                       // 1,048,576 B
  unsigned short* wbw = (unsigned short*)(ws + 1048576);           //   589,824 B
  float*          csq = (float*)(ws + 1048576 + 589824);           //     8,192 B

  rbfn_prep<<<800, 256, 0, stream>>>(centers, W, cbw, wbw, csq);
  rbfn_main<<<256, 512, 0, stream>>>(X, beta, bias, cbw, wbw, csq, out);
}